// Round 4
// baseline (468.617 us; speedup 1.0000x reference)
//
#include <hip/hip_runtime.h>
#include <math.h>

#define ND 512
#define NK 32

typedef __attribute__((ext_vector_type(8))) short short8;
typedef __attribute__((ext_vector_type(4))) float f32x4;
typedef __attribute__((address_space(1))) const unsigned int glds_src;
typedef __attribute__((address_space(3))) unsigned int glds_dst;

__device__ inline unsigned short f2bf(float x) {
  unsigned u = __float_as_uint(x);
  unsigned r = (u + 0x7fffu + ((u >> 16) & 1u)) >> 16;  // RNE
  return (unsigned short)r;
}
__device__ inline float bf2f(unsigned short h) {
  return __uint_as_float(((unsigned)h) << 16);
}
__device__ inline void gload_lds16(const void* g, void* l) {
  __builtin_amdgcn_global_load_lds((glds_src*)g, (glds_dst*)l, 16, 0, 0);
}

// ---------------- mask dtype detection ----------------
__global__ void detect_mask_kernel(const unsigned int* __restrict__ m, int nwords,
                                   int* __restrict__ flag) {
  int local = 0;
  for (int i = blockIdx.x * blockDim.x + threadIdx.x; i < nwords;
       i += gridDim.x * blockDim.x) {
    if (m[i] > 1u) local = 1;
  }
  if (__any(local)) {
    if ((threadIdx.x & 63) == 0) atomicOr(flag, 1);
  }
}

// ---------------- panel converter ----------------
// Encode f32 [rows, Kd*32] row-major into per-row swizzled hi/lo bf16 image:
// per k-block (128 B): 4 groups of [hi 16B | lo 16B] for k-slots s=0..3,
// XOR-swizzled by ((row&7)<<4) on byte-in-128B. Pad rows zero-filled.
__global__ void convert_panel(const float* __restrict__ src,
                              unsigned char* __restrict__ dst,
                              int rows_src, int rows_pad, int Kd) {
  const long long total = (long long)rows_pad * Kd * 4;
  const int cpr = Kd * 4;
  for (long long c = (long long)blockIdx.x * blockDim.x + threadIdx.x; c < total;
       c += (long long)gridDim.x * blockDim.x) {
    const int r = (int)(c / cpr);
    const int rem = (int)(c % cpr);
    const int kb = rem >> 2;
    const int s = rem & 3;
    const int sw = (r & 7) << 4;
    unsigned short h[8], l[8];
    if (r < rows_src) {
      const float* p = src + (size_t)r * (Kd * 32) + kb * 32 + s * 8;
      #pragma unroll
      for (int j = 0; j < 8; j++) {
        const float v = p[j];
        h[j] = f2bf(v);
        l[j] = f2bf(v - bf2f(h[j]));
      }
    } else {
      #pragma unroll
      for (int j = 0; j < 8; j++) { h[j] = 0; l[j] = 0; }
    }
    uint4 hv, lv;
    hv.x = (unsigned)h[0] | ((unsigned)h[1] << 16);
    hv.y = (unsigned)h[2] | ((unsigned)h[3] << 16);
    hv.z = (unsigned)h[4] | ((unsigned)h[5] << 16);
    hv.w = (unsigned)h[6] | ((unsigned)h[7] << 16);
    lv.x = (unsigned)l[0] | ((unsigned)l[1] << 16);
    lv.y = (unsigned)l[2] | ((unsigned)l[3] << 16);
    lv.z = (unsigned)l[4] | ((unsigned)l[5] << 16);
    lv.w = (unsigned)l[6] | ((unsigned)l[7] << 16);
    unsigned char* rowb = dst + (size_t)r * (Kd * 128) + kb * 128;
    *(uint4*)(rowb + ((s * 32) ^ sw)) = hv;
    *(uint4*)(rowb + ((s * 32 + 16) ^ sw)) = lv;
  }
}

// ---------------- split-bf16 MFMA GEMM on panel images ----------------
// 2-phase double-buffered pipeline (T3-min): issue next-tile global_load_lds
// BEFORE computing current tile; one vmcnt(0) + raw s_barrier per K-step.
// 128x128 tile, BK=32, 256 thr / 4 waves, 4x4 frags 16x16x32, 3 MFMA per
// frag pair (hh+hl+lh ~ f32 accuracy).
template<bool SPLIT, bool TANH>
__global__ __launch_bounds__(256, 2) void gemm_mfma(
    const unsigned char* __restrict__ A1, const unsigned char* __restrict__ A2,
    const unsigned char* __restrict__ B, float* __restrict__ C,
    int M, int N, int KB)  // K = KB*32
{
  __shared__ unsigned char AsP[2][16384];
  __shared__ unsigned char BsP[2][16384];
  const int tid = threadIdx.x;
  const int lane = tid & 63;
  const int wv = tid >> 6;
  const int wr = wv >> 1, wc = wv & 1;
  const int bm = blockIdx.y * 128, bn = blockIdx.x * 128;
  const size_t brstride = (size_t)KB * 128;
  const size_t arstride = SPLIT ? 2048 : (size_t)KB * 128;

  f32x4 acc[4][4];
  #pragma unroll
  for (int i = 0; i < 4; i++)
    #pragma unroll
    for (int j = 0; j < 4; j++) acc[i][j] = (f32x4){0.f, 0.f, 0.f, 0.f};

  const int s16 = (lane >> 4) * 32;
  const int lrow0 = (wv << 3) + (lane >> 3);   // 0..31
  const int lbyte = (lane & 7) * 16;

  auto stage = [&](int kbx, unsigned char* bufA, unsigned char* bufB) {
    const unsigned char* Ab;
    int akb;
    if (SPLIT) { Ab = (kbx < 16) ? A1 : A2; akb = kbx & 15; }
    else       { Ab = A1; akb = kbx; }
    #pragma unroll
    for (int i = 0; i < 4; i++) {
      const int lrow = i * 32 + lrow0;
      gload_lds16(Ab + (size_t)(bm + lrow) * arstride + (size_t)akb * 128 + lbyte,
                  bufA + i * 4096 + wv * 1024);
      gload_lds16(B + (size_t)(bn + lrow) * brstride + (size_t)kbx * 128 + lbyte,
                  bufB + i * 4096 + wv * 1024);
    }
  };

  // prologue: stage k-block 0 into buffer 0
  stage(0, AsP[0], BsP[0]);
  asm volatile("s_waitcnt vmcnt(0)" ::: "memory");
  __builtin_amdgcn_s_barrier();

  int cur = 0;
  for (int kb = 0; kb < KB; kb++) {
    // issue next-tile loads (fly under this tile's ds_read + MFMA)
    if (kb + 1 < KB) stage(kb + 1, AsP[cur ^ 1], BsP[cur ^ 1]);

    const unsigned char* Ac = AsP[cur];
    const unsigned char* Bc = BsP[cur];
    short8 bh[4], bl[4];
    #pragma unroll
    for (int fn = 0; fn < 4; fn++) {
      const int row = wc * 64 + fn * 16 + (lane & 15);
      const int sw = (row & 7) << 4;
      bh[fn] = *(const short8*)(Bc + row * 128 + (s16 ^ sw));
      bl[fn] = *(const short8*)(Bc + row * 128 + ((s16 + 16) ^ sw));
    }
    __builtin_amdgcn_s_setprio(1);
    #pragma unroll
    for (int fm = 0; fm < 4; fm++) {
      const int row = wr * 64 + fm * 16 + (lane & 15);
      const int sw = (row & 7) << 4;
      const short8 ah = *(const short8*)(Ac + row * 128 + (s16 ^ sw));
      const short8 al = *(const short8*)(Ac + row * 128 + ((s16 + 16) ^ sw));
      #pragma unroll
      for (int fn = 0; fn < 4; fn++) {
        acc[fm][fn] = __builtin_amdgcn_mfma_f32_16x16x32_bf16(ah, bh[fn], acc[fm][fn], 0, 0, 0);
        acc[fm][fn] = __builtin_amdgcn_mfma_f32_16x16x32_bf16(ah, bl[fn], acc[fm][fn], 0, 0, 0);
        acc[fm][fn] = __builtin_amdgcn_mfma_f32_16x16x32_bf16(al, bh[fn], acc[fm][fn], 0, 0, 0);
      }
    }
    __builtin_amdgcn_s_setprio(0);
    // drain this wave's prefetch, then sync: buffer cur^1 fully staged for all
    asm volatile("s_waitcnt vmcnt(0)" ::: "memory");
    __builtin_amdgcn_s_barrier();
    cur ^= 1;
  }

  // C/D map: col=lane&15, row=(lane>>4)*4+j
  #pragma unroll
  for (int fm = 0; fm < 4; fm++) {
    #pragma unroll
    for (int fn = 0; fn < 4; fn++) {
      const int col = bn + wc * 64 + fn * 16 + (lane & 15);
      #pragma unroll
      for (int j = 0; j < 4; j++) {
        const int row = bm + wr * 64 + fm * 16 + (lane >> 4) * 4 + j;
        if (row < M) {
          float v = acc[fm][fn][j];
          if (TANH) v = tanhf(v);
          C[(size_t)row * N + col] = v;
        }
      }
    }
  }
}

// ---------------- fused scores + softmax + aggregate ----------------
// One block (512 thr / 8 waves) per row; neigh streamed once through regs.
// Output written directly as panel image (hi/lo bf16, swizzled) for gemm2.
__global__ __launch_bounds__(512) void attn_fused(
    const float* __restrict__ neigh,   // [N, 32, 512]
    const float* __restrict__ x,       // [N, 512] f32
    const void* __restrict__ mask,     // [N, 32] int32 or u8 (see flag)
    const int* __restrict__ mask_is_u8,
    unsigned char* __restrict__ aggP)  // panel image, 2048 B/row
{
  __shared__ float x_s[ND];
  __shared__ float part[8][ND];
  __shared__ float sc_s[NK];
  __shared__ float attn_s[NK];
  __shared__ unsigned char img[2048];
  const int n = blockIdx.x;
  const int tid = threadIdx.x;
  const int wv = tid >> 6;
  const int lane = tid & 63;

  x_s[tid] = x[(size_t)n * ND + tid];
  __syncthreads();

  const float4 xa = *(const float4*)&x_s[lane * 4];
  const float4 xb = *(const float4*)&x_s[256 + lane * 4];

  const float4* nbase = (const float4*)(neigh + ((size_t)n * NK + wv * 4) * ND);
  float4 na[4], nb[4];
  #pragma unroll
  for (int j = 0; j < 4; j++) {
    na[j] = nbase[j * 128 + lane];
    nb[j] = nbase[j * 128 + 64 + lane];
  }

  #pragma unroll
  for (int j = 0; j < 4; j++) {
    float p = na[j].x * xa.x + na[j].y * xa.y + na[j].z * xa.z + na[j].w * xa.w
            + nb[j].x * xb.x + nb[j].y * xb.y + nb[j].z * xb.z + nb[j].w * xb.w;
    #pragma unroll
    for (int off = 32; off; off >>= 1) p += __shfl_xor(p, off);
    if (lane == 0) sc_s[wv * 4 + j] = p;
  }
  __syncthreads();

  if (tid < NK) {
    const int mk = (*mask_is_u8)
        ? (int)((const unsigned char*)mask)[(size_t)n * NK + tid]
        : ((const int*)mask)[(size_t)n * NK + tid];
    float s = mk ? -3.4e38f : sc_s[tid];
    float m = s;
    #pragma unroll
    for (int off = 16; off; off >>= 1) m = fmaxf(m, __shfl_xor(m, off, 32));
    const float p = mk ? 0.f : expf(s - m);
    float t = p;
    #pragma unroll
    for (int off = 16; off; off >>= 1) t += __shfl_xor(t, off, 32);
    attn_s[tid] = p / t;
  }
  __syncthreads();

  float4 acc0 = make_float4(0.f, 0.f, 0.f, 0.f);
  float4 acc1 = make_float4(0.f, 0.f, 0.f, 0.f);
  #pragma unroll
  for (int j = 0; j < 4; j++) {
    const float w = attn_s[wv * 4 + j];
    acc0.x = fmaf(w, na[j].x, acc0.x);
    acc0.y = fmaf(w, na[j].y, acc0.y);
    acc0.z = fmaf(w, na[j].z, acc0.z);
    acc0.w = fmaf(w, na[j].w, acc0.w);
    acc1.x = fmaf(w, nb[j].x, acc1.x);
    acc1.y = fmaf(w, nb[j].y, acc1.y);
    acc1.z = fmaf(w, nb[j].z, acc1.z);
    acc1.w = fmaf(w, nb[j].w, acc1.w);
  }
  *(float4*)&part[wv][lane * 4] = acc0;
  *(float4*)&part[wv][256 + lane * 4] = acc1;
  __syncthreads();
  float ssum = 0.f;
  #pragma unroll
  for (int w = 0; w < 8; w++) ssum += part[w][tid];

  // encode into panel-image row (k = tid)
  {
    const int sw = (n & 7) << 4;
    const int kb = tid >> 5;
    const int bu = ((tid >> 3) & 3) * 32 + (tid & 7) * 2;   // bit4 == 0
    const unsigned short h = f2bf(ssum);
    const unsigned short l = f2bf(ssum - bf2f(h));
    *(unsigned short*)(img + kb * 128 + (bu ^ sw)) = h;
    *(unsigned short*)(img + kb * 128 + ((bu | 16) ^ sw)) = l;
  }
  __syncthreads();
  if (tid < 128) {
    *(uint4*)(aggP + (size_t)n * 2048 + tid * 16) = *(const uint4*)(img + tid * 16);
  }
}

extern "C" void kernel_launch(void* const* d_in, const int* in_sizes, int n_in,
                              void* d_out, int out_size, void* d_ws, size_t ws_size,
                              hipStream_t stream) {
  const float* prev  = (const float*)d_in[0];   // [N, 512]
  const float* neigh = (const float*)d_in[1];   // [N, 32, 512]
  const void*  mask  = d_in[2];                 // [N, 32]
  const float* W1    = (const float*)d_in[3];   // [512, 512]
  const float* Wa    = (const float*)d_in[4];   // [512, 1024]
  float* out = (float*)d_out;
  const int N = in_sizes[0] / ND;               // 20000
  const int Mp = ((N + 127) / 128) * 128;       // 20096

  unsigned char* ws = (unsigned char*)d_ws;
  float*         x     = (float*)ws;                         // N*2048 B
  unsigned char* prevP = ws + (size_t)N * 2048;              // Mp*2048
  unsigned char* aggP  = prevP + (size_t)Mp * 2048;          // Mp*2048
  unsigned char* W1P   = aggP + (size_t)Mp * 2048;           // 512*2048
  unsigned char* WaP   = W1P + (size_t)512 * 2048;           // 512*4096
  int*           flag  = (int*)(WaP + (size_t)512 * 4096);

  hipMemsetAsync(flag, 0, sizeof(int), stream);
  detect_mask_kernel<<<64, 256, 0, stream>>>((const unsigned int*)mask,
                                             (N * NK) / 4, flag);

  // pre-encode GEMM operands into panel images
  convert_panel<<<2048, 256, 0, stream>>>(prev, prevP, N, Mp, 16);
  convert_panel<<<256, 256, 0, stream>>>(W1, W1P, 512, 512, 16);
  convert_panel<<<512, 256, 0, stream>>>(Wa, WaP, 512, 512, 32);
  if (Mp > N)
    hipMemsetAsync(aggP + (size_t)N * 2048, 0, (size_t)(Mp - N) * 2048, stream);

  dim3 g1(ND / 128, Mp / 128);  // bn fast -> blocks sharing A-panel adjacent

  // x = prev @ W1^T
  gemm_mfma<false, false><<<g1, 256, 0, stream>>>(prevP, nullptr, W1P, x, N, ND, 16);

  // scores -> softmax -> agg (neigh streamed once; agg emitted as panel image)
  attn_fused<<<N, 512, 0, stream>>>(neigh, x, mask, flag, aggP);

  // out = tanh(concat(agg, prev) @ Wa^T)
  gemm_mfma<true, true><<<g1, 256, 0, stream>>>(aggP, prevP, WaP, out, N, ND, 32);
}

// Round 5
// 419.329 us; speedup vs baseline: 1.1175x; 1.1175x over previous
//
#include <hip/hip_runtime.h>
#include <math.h>

#define ND 512
#define NK 32

typedef __attribute__((ext_vector_type(8))) short short8;
typedef __attribute__((ext_vector_type(4))) float f32x4;
typedef __attribute__((address_space(1))) const unsigned int glds_src;
typedef __attribute__((address_space(3))) unsigned int glds_dst;

__device__ inline unsigned short f2bf(float x) {
  unsigned u = __float_as_uint(x);
  unsigned r = (u + 0x7fffu + ((u >> 16) & 1u)) >> 16;  // RNE
  return (unsigned short)r;
}
__device__ inline float bf2f(unsigned short h) {
  return __uint_as_float(((unsigned)h) << 16);
}
__device__ inline void gload_lds16(const void* g, void* l) {
  __builtin_amdgcn_global_load_lds((glds_src*)g, (glds_dst*)l, 16, 0, 0);
}

// bijective XCD chunking (m204): each of 8 XCDs gets a contiguous wgid run
__device__ inline int xcd_swz(int orig, int nwg) {
  const int q = nwg >> 3, r = nwg & 7;
  const int xcd = orig & 7, pos = orig >> 3;
  return (xcd < r ? xcd * (q + 1) : r * (q + 1) + (xcd - r) * q) + pos;
}

// ---------------- mask dtype detection ----------------
__global__ void detect_mask_kernel(const unsigned int* __restrict__ m, int nwords,
                                   int* __restrict__ flag) {
  int local = 0;
  for (int i = blockIdx.x * blockDim.x + threadIdx.x; i < nwords;
       i += gridDim.x * blockDim.x) {
    if (m[i] > 1u) local = 1;
  }
  if (__any(local)) {
    if ((threadIdx.x & 63) == 0) atomicOr(flag, 1);
  }
}

// ---------------- panel converter ----------------
// Encode f32 [rows, Kd*32] row-major into per-row swizzled hi/lo bf16 image:
// per k-block (128 B): 4 groups of [hi 16B | lo 16B] for k-slots s=0..3,
// XOR-swizzled by ((row&7)<<4) on byte-in-128B. Pad rows zero-filled.
__global__ void convert_panel(const float* __restrict__ src,
                              unsigned char* __restrict__ dst,
                              int rows_src, int rows_pad, int Kd) {
  const long long total = (long long)rows_pad * Kd * 4;
  const int cpr = Kd * 4;
  for (long long c = (long long)blockIdx.x * blockDim.x + threadIdx.x; c < total;
       c += (long long)gridDim.x * blockDim.x) {
    const int r = (int)(c / cpr);
    const int rem = (int)(c % cpr);
    const int kb = rem >> 2;
    const int s = rem & 3;
    const int sw = (r & 7) << 4;
    unsigned short h[8], l[8];
    if (r < rows_src) {
      const float* p = src + (size_t)r * (Kd * 32) + kb * 32 + s * 8;
      #pragma unroll
      for (int j = 0; j < 8; j++) {
        const float v = p[j];
        h[j] = f2bf(v);
        l[j] = f2bf(v - bf2f(h[j]));
      }
    } else {
      #pragma unroll
      for (int j = 0; j < 8; j++) { h[j] = 0; l[j] = 0; }
    }
    uint4 hv, lv;
    hv.x = (unsigned)h[0] | ((unsigned)h[1] << 16);
    hv.y = (unsigned)h[2] | ((unsigned)h[3] << 16);
    hv.z = (unsigned)h[4] | ((unsigned)h[5] << 16);
    hv.w = (unsigned)h[6] | ((unsigned)h[7] << 16);
    lv.x = (unsigned)l[0] | ((unsigned)l[1] << 16);
    lv.y = (unsigned)l[2] | ((unsigned)l[3] << 16);
    lv.z = (unsigned)l[4] | ((unsigned)l[5] << 16);
    lv.w = (unsigned)l[6] | ((unsigned)l[7] << 16);
    unsigned char* rowb = dst + (size_t)r * (Kd * 128) + kb * 128;
    *(uint4*)(rowb + ((s * 32) ^ sw)) = hv;
    *(uint4*)(rowb + ((s * 32 + 16) ^ sw)) = lv;
  }
}

// ---------------- split-bf16 MFMA GEMM on panel images ----------------
// Single-buffered m97 structure (R4's explicit dbuf cost occupancy: 3->2
// blocks/CU — reverted). 128x128 tile, BK=32, 256 thr / 4 waves, 4x4 frags
// of 16x16x32, 3 MFMA per frag pair (hh+hl+lh ~ f32). 1-D grid, XCD-swizzled:
// bn innermost so the 4 blocks sharing an A-panel land on one XCD's L2.
template<bool SPLIT, bool TANH>
__global__ __launch_bounds__(256, 3) void gemm_mfma(
    const unsigned char* __restrict__ A1, const unsigned char* __restrict__ A2,
    const unsigned char* __restrict__ B, float* __restrict__ C,
    int M, int N, int KB)  // K = KB*32; N == 512 (4 col-blocks)
{
  __shared__ unsigned char AsP[16384];
  __shared__ unsigned char BsP[16384];
  const int tid = threadIdx.x;
  const int lane = tid & 63;
  const int wv = tid >> 6;
  const int wr = wv >> 1, wc = wv & 1;
  const int wgid = xcd_swz(blockIdx.x, gridDim.x);
  const int bm = (wgid >> 2) * 128, bn = (wgid & 3) * 128;
  const size_t brstride = (size_t)KB * 128;
  const size_t arstride = SPLIT ? 2048 : (size_t)KB * 128;

  f32x4 acc[4][4];
  #pragma unroll
  for (int i = 0; i < 4; i++)
    #pragma unroll
    for (int j = 0; j < 4; j++) acc[i][j] = (f32x4){0.f, 0.f, 0.f, 0.f};

  const int s16 = (lane >> 4) * 32;
  const int lrow0 = (wv << 3) + (lane >> 3);   // 0..31
  const int lbyte = (lane & 7) * 16;

  for (int kb = 0; kb < KB; kb++) {
    const unsigned char* Ab;
    int akb;
    if (SPLIT) { Ab = (kb < 16) ? A1 : A2; akb = kb & 15; }
    else       { Ab = A1; akb = kb; }
    #pragma unroll
    for (int i = 0; i < 4; i++) {
      const int lrow = i * 32 + lrow0;
      gload_lds16(Ab + (size_t)(bm + lrow) * arstride + (size_t)akb * 128 + lbyte,
                  AsP + i * 4096 + wv * 1024);
      gload_lds16(B + (size_t)(bn + lrow) * brstride + (size_t)kb * 128 + lbyte,
                  BsP + i * 4096 + wv * 1024);
    }
    __syncthreads();

    short8 bh[4], bl[4];
    #pragma unroll
    for (int fn = 0; fn < 4; fn++) {
      const int row = wc * 64 + fn * 16 + (lane & 15);
      const int sw = (row & 7) << 4;
      bh[fn] = *(const short8*)(BsP + row * 128 + (s16 ^ sw));
      bl[fn] = *(const short8*)(BsP + row * 128 + ((s16 + 16) ^ sw));
    }
    #pragma unroll
    for (int fm = 0; fm < 4; fm++) {
      const int row = wr * 64 + fm * 16 + (lane & 15);
      const int sw = (row & 7) << 4;
      const short8 ah = *(const short8*)(AsP + row * 128 + (s16 ^ sw));
      const short8 al = *(const short8*)(AsP + row * 128 + ((s16 + 16) ^ sw));
      #pragma unroll
      for (int fn = 0; fn < 4; fn++) {
        acc[fm][fn] = __builtin_amdgcn_mfma_f32_16x16x32_bf16(ah, bh[fn], acc[fm][fn], 0, 0, 0);
        acc[fm][fn] = __builtin_amdgcn_mfma_f32_16x16x32_bf16(ah, bl[fn], acc[fm][fn], 0, 0, 0);
        acc[fm][fn] = __builtin_amdgcn_mfma_f32_16x16x32_bf16(al, bh[fn], acc[fm][fn], 0, 0, 0);
      }
    }
    __syncthreads();
  }

  // C/D map: col=lane&15, row=(lane>>4)*4+j
  #pragma unroll
  for (int fm = 0; fm < 4; fm++) {
    #pragma unroll
    for (int fn = 0; fn < 4; fn++) {
      const int col = bn + wc * 64 + fn * 16 + (lane & 15);
      #pragma unroll
      for (int j = 0; j < 4; j++) {
        const int row = bm + wr * 64 + fm * 16 + (lane >> 4) * 4 + j;
        if (row < M) {
          float v = acc[fm][fn][j];
          if (TANH) v = tanhf(v);
          C[(size_t)row * N + col] = v;
        }
      }
    }
  }
}

// ---------------- fused scores + softmax + aggregate ----------------
// One block (512 thr / 8 waves) per row; neigh streamed once through regs.
// Output written directly as panel image (hi/lo bf16, swizzled) for gemm2.
__global__ __launch_bounds__(512) void attn_fused(
    const float* __restrict__ neigh,   // [N, 32, 512]
    const float* __restrict__ x,       // [N, 512] f32
    const void* __restrict__ mask,     // [N, 32] int32 or u8 (see flag)
    const int* __restrict__ mask_is_u8,
    unsigned char* __restrict__ aggP)  // panel image, 2048 B/row
{
  __shared__ float x_s[ND];
  __shared__ float part[8][ND];
  __shared__ float sc_s[NK];
  __shared__ float attn_s[NK];
  __shared__ unsigned char img[2048];
  const int n = blockIdx.x;
  const int tid = threadIdx.x;
  const int wv = tid >> 6;
  const int lane = tid & 63;

  x_s[tid] = x[(size_t)n * ND + tid];
  __syncthreads();

  const float4 xa = *(const float4*)&x_s[lane * 4];
  const float4 xb = *(const float4*)&x_s[256 + lane * 4];

  const float4* nbase = (const float4*)(neigh + ((size_t)n * NK + wv * 4) * ND);
  float4 na[4], nb[4];
  #pragma unroll
  for (int j = 0; j < 4; j++) {
    na[j] = nbase[j * 128 + lane];
    nb[j] = nbase[j * 128 + 64 + lane];
  }

  #pragma unroll
  for (int j = 0; j < 4; j++) {
    float p = na[j].x * xa.x + na[j].y * xa.y + na[j].z * xa.z + na[j].w * xa.w
            + nb[j].x * xb.x + nb[j].y * xb.y + nb[j].z * xb.z + nb[j].w * xb.w;
    #pragma unroll
    for (int off = 32; off; off >>= 1) p += __shfl_xor(p, off);
    if (lane == 0) sc_s[wv * 4 + j] = p;
  }
  __syncthreads();

  if (tid < NK) {
    const int mk = (*mask_is_u8)
        ? (int)((const unsigned char*)mask)[(size_t)n * NK + tid]
        : ((const int*)mask)[(size_t)n * NK + tid];
    float s = mk ? -3.4e38f : sc_s[tid];
    float m = s;
    #pragma unroll
    for (int off = 16; off; off >>= 1) m = fmaxf(m, __shfl_xor(m, off, 32));
    const float p = mk ? 0.f : expf(s - m);
    float t = p;
    #pragma unroll
    for (int off = 16; off; off >>= 1) t += __shfl_xor(t, off, 32);
    attn_s[tid] = p / t;
  }
  __syncthreads();

  float4 acc0 = make_float4(0.f, 0.f, 0.f, 0.f);
  float4 acc1 = make_float4(0.f, 0.f, 0.f, 0.f);
  #pragma unroll
  for (int j = 0; j < 4; j++) {
    const float w = attn_s[wv * 4 + j];
    acc0.x = fmaf(w, na[j].x, acc0.x);
    acc0.y = fmaf(w, na[j].y, acc0.y);
    acc0.z = fmaf(w, na[j].z, acc0.z);
    acc0.w = fmaf(w, na[j].w, acc0.w);
    acc1.x = fmaf(w, nb[j].x, acc1.x);
    acc1.y = fmaf(w, nb[j].y, acc1.y);
    acc1.z = fmaf(w, nb[j].z, acc1.z);
    acc1.w = fmaf(w, nb[j].w, acc1.w);
  }
  *(float4*)&part[wv][lane * 4] = acc0;
  *(float4*)&part[wv][256 + lane * 4] = acc1;
  __syncthreads();
  float ssum = 0.f;
  #pragma unroll
  for (int w = 0; w < 8; w++) ssum += part[w][tid];

  // encode into panel-image row (k = tid)
  {
    const int sw = (n & 7) << 4;
    const int kb = tid >> 5;
    const int bu = ((tid >> 3) & 3) * 32 + (tid & 7) * 2;   // bit4 == 0
    const unsigned short h = f2bf(ssum);
    const unsigned short l = f2bf(ssum - bf2f(h));
    *(unsigned short*)(img + kb * 128 + (bu ^ sw)) = h;
    *(unsigned short*)(img + kb * 128 + ((bu | 16) ^ sw)) = l;
  }
  __syncthreads();
  if (tid < 128) {
    *(uint4*)(aggP + (size_t)n * 2048 + tid * 16) = *(const uint4*)(img + tid * 16);
  }
}

extern "C" void kernel_launch(void* const* d_in, const int* in_sizes, int n_in,
                              void* d_out, int out_size, void* d_ws, size_t ws_size,
                              hipStream_t stream) {
  const float* prev  = (const float*)d_in[0];   // [N, 512]
  const float* neigh = (const float*)d_in[1];   // [N, 32, 512]
  const void*  mask  = d_in[2];                 // [N, 32]
  const float* W1    = (const float*)d_in[3];   // [512, 512]
  const float* Wa    = (const float*)d_in[4];   // [512, 1024]
  float* out = (float*)d_out;
  const int N = in_sizes[0] / ND;               // 20000
  const int Mp = ((N + 127) / 128) * 128;       // 20096

  unsigned char* ws = (unsigned char*)d_ws;
  float*         x     = (float*)ws;                         // N*2048 B
  unsigned char* prevP = ws + (size_t)N * 2048;              // Mp*2048
  unsigned char* aggP  = prevP + (size_t)Mp * 2048;          // Mp*2048
  unsigned char* W1P   = aggP + (size_t)Mp * 2048;           // 512*2048
  unsigned char* WaP   = W1P + (size_t)512 * 2048;           // 512*4096
  int*           flag  = (int*)(WaP + (size_t)512 * 4096);

  hipMemsetAsync(flag, 0, sizeof(int), stream);
  detect_mask_kernel<<<64, 256, 0, stream>>>((const unsigned int*)mask,
                                             (N * NK) / 4, flag);

  // pre-encode GEMM operands into panel images
  convert_panel<<<2048, 256, 0, stream>>>(prev, prevP, N, Mp, 16);
  convert_panel<<<256, 256, 0, stream>>>(W1, W1P, 512, 512, 16);
  convert_panel<<<512, 256, 0, stream>>>(Wa, WaP, 512, 512, 32);
  if (Mp > N)
    hipMemsetAsync(aggP + (size_t)N * 2048, 0, (size_t)(Mp - N) * 2048, stream);

  const int nwg = (Mp / 128) * 4;  // 1-D grid, bn innermost, XCD-swizzled

  // x = prev @ W1^T
  gemm_mfma<false, false><<<nwg, 256, 0, stream>>>(prevP, nullptr, W1P, x, N, ND, 16);

  // scores -> softmax -> agg (neigh streamed once; agg emitted as panel image)
  attn_fused<<<N, 512, 0, stream>>>(neigh, x, mask, flag, aggP);

  // out = tanh(concat(agg, prev) @ Wa^T)
  gemm_mfma<true, true><<<nwg, 256, 0, stream>>>(aggP, prevP, WaP, out, N, ND, 32);
}

// Round 6
// 408.510 us; speedup vs baseline: 1.1471x; 1.0265x over previous
//
#include <hip/hip_runtime.h>
#include <math.h>

#define ND 512
#define NK 32

typedef __attribute__((ext_vector_type(8))) short short8;
typedef __attribute__((ext_vector_type(4))) float f32x4;
typedef __attribute__((address_space(1))) const unsigned int glds_src;
typedef __attribute__((address_space(3))) unsigned int glds_dst;

__device__ inline unsigned short f2bf(float x) {
  unsigned u = __float_as_uint(x);
  unsigned r = (u + 0x7fffu + ((u >> 16) & 1u)) >> 16;  // RNE
  return (unsigned short)r;
}
__device__ inline float bf2f(unsigned short h) {
  return __uint_as_float(((unsigned)h) << 16);
}
__device__ inline void gload_lds16(const void* g, void* l) {
  __builtin_amdgcn_global_load_lds((glds_src*)g, (glds_dst*)l, 16, 0, 0);
}

// bijective XCD chunking (m204): each of 8 XCDs gets a contiguous wgid run
__device__ inline int xcd_swz(int orig, int nwg) {
  const int q = nwg >> 3, r = nwg & 7;
  const int xcd = orig & 7, pos = orig >> 3;
  return (xcd < r ? xcd * (q + 1) : r * (q + 1) + (xcd - r) * q) + pos;
}

// ---------------- mask dtype detection ----------------
__global__ void detect_mask_kernel(const unsigned int* __restrict__ m, int nwords,
                                   int* __restrict__ flag) {
  int local = 0;
  for (int i = blockIdx.x * blockDim.x + threadIdx.x; i < nwords;
       i += gridDim.x * blockDim.x) {
    if (m[i] > 1u) local = 1;
  }
  if (__any(local)) {
    if ((threadIdx.x & 63) == 0) atomicOr(flag, 1);
  }
}

// ---------------- fused panel converter (prev + W1 + Wa in one launch) ----
// Encode f32 [rows, Kd*32] row-major into per-row swizzled hi/lo bf16 image:
// per k-block (128 B): 4 groups of [hi 16B | lo 16B] for k-slots s=0..3,
// XOR-swizzled by ((row&7)<<4) on byte-in-128B. Pad rows zero-filled.
__device__ inline void conv_chunk(const float* __restrict__ src,
                                  unsigned char* __restrict__ dst,
                                  int rows_src, int Kd, long long c) {
  const int cpr = Kd * 4;
  const int r = (int)(c / cpr);
  const int rem = (int)(c % cpr);
  const int kb = rem >> 2;
  const int s = rem & 3;
  const int sw = (r & 7) << 4;
  unsigned short h[8], l[8];
  if (r < rows_src) {
    const float* p = src + (size_t)r * (Kd * 32) + kb * 32 + s * 8;
    #pragma unroll
    for (int j = 0; j < 8; j++) {
      const float v = p[j];
      h[j] = f2bf(v);
      l[j] = f2bf(v - bf2f(h[j]));
    }
  } else {
    #pragma unroll
    for (int j = 0; j < 8; j++) { h[j] = 0; l[j] = 0; }
  }
  uint4 hv, lv;
  hv.x = (unsigned)h[0] | ((unsigned)h[1] << 16);
  hv.y = (unsigned)h[2] | ((unsigned)h[3] << 16);
  hv.z = (unsigned)h[4] | ((unsigned)h[5] << 16);
  hv.w = (unsigned)h[6] | ((unsigned)h[7] << 16);
  lv.x = (unsigned)l[0] | ((unsigned)l[1] << 16);
  lv.y = (unsigned)l[2] | ((unsigned)l[3] << 16);
  lv.z = (unsigned)l[4] | ((unsigned)l[5] << 16);
  lv.w = (unsigned)l[6] | ((unsigned)l[7] << 16);
  unsigned char* rowb = dst + (size_t)r * (Kd * 128) + kb * 128;
  *(uint4*)(rowb + ((s * 32) ^ sw)) = hv;
  *(uint4*)(rowb + ((s * 32 + 16) ^ sw)) = lv;
}

__global__ void convert_panels3(const float* __restrict__ prev, unsigned char* __restrict__ prevP,
                                int Np, int Mp,
                                const float* __restrict__ W1, unsigned char* __restrict__ W1P,
                                const float* __restrict__ Wa, unsigned char* __restrict__ WaP) {
  const long long c0 = (long long)Mp * 64;          // prev chunks (Kd=16)
  const long long c1 = c0 + 512 * 64;               // + W1 chunks (Kd=16)
  const long long c2 = c1 + 512 * 128;              // + Wa chunks (Kd=32)
  for (long long c = (long long)blockIdx.x * blockDim.x + threadIdx.x; c < c2;
       c += (long long)gridDim.x * blockDim.x) {
    if (c < c0)      conv_chunk(prev, prevP, Np, 16, c);
    else if (c < c1) conv_chunk(W1, W1P, 512, 16, c - c0);
    else             conv_chunk(Wa, WaP, 512, 32, c - c1);
  }
}

// ---------------- split-bf16 MFMA GEMM on panel images ----------------
// Single-buffered m97 structure. 128x128 tile, BK=32, 256 thr / 4 waves,
// 4x4 frags of 16x16x32. LH ? 3 MFMA (hh+hl+lh, ~f32) : 2 MFMA (hh+hl —
// drops A-lo term; OK for tanh-output path, NOT for the score path).
// 1-D grid, XCD-swizzled, bn innermost (A-panel L2 reuse).
template<bool SPLIT, bool TANH, bool LH>
__global__ __launch_bounds__(256, 3) void gemm_mfma(
    const unsigned char* __restrict__ A1, const unsigned char* __restrict__ A2,
    const unsigned char* __restrict__ B, float* __restrict__ C,
    int M, int N, int KB)  // K = KB*32; N == 512 (4 col-blocks)
{
  __shared__ unsigned char AsP[16384];
  __shared__ unsigned char BsP[16384];
  const int tid = threadIdx.x;
  const int lane = tid & 63;
  const int wv = tid >> 6;
  const int wr = wv >> 1, wc = wv & 1;
  const int wgid = xcd_swz(blockIdx.x, gridDim.x);
  const int bm = (wgid >> 2) * 128, bn = (wgid & 3) * 128;
  const size_t brstride = (size_t)KB * 128;
  const size_t arstride = SPLIT ? 2048 : (size_t)KB * 128;

  f32x4 acc[4][4];
  #pragma unroll
  for (int i = 0; i < 4; i++)
    #pragma unroll
    for (int j = 0; j < 4; j++) acc[i][j] = (f32x4){0.f, 0.f, 0.f, 0.f};

  const int s16 = (lane >> 4) * 32;
  const int lrow0 = (wv << 3) + (lane >> 3);   // 0..31
  const int lbyte = (lane & 7) * 16;

  for (int kb = 0; kb < KB; kb++) {
    const unsigned char* Ab;
    int akb;
    if (SPLIT) { Ab = (kb < 16) ? A1 : A2; akb = kb & 15; }
    else       { Ab = A1; akb = kb; }
    #pragma unroll
    for (int i = 0; i < 4; i++) {
      const int lrow = i * 32 + lrow0;
      gload_lds16(Ab + (size_t)(bm + lrow) * arstride + (size_t)akb * 128 + lbyte,
                  AsP + i * 4096 + wv * 1024);
      gload_lds16(B + (size_t)(bn + lrow) * brstride + (size_t)kb * 128 + lbyte,
                  BsP + i * 4096 + wv * 1024);
    }
    __syncthreads();

    short8 bh[4], bl[4];
    #pragma unroll
    for (int fn = 0; fn < 4; fn++) {
      const int row = wc * 64 + fn * 16 + (lane & 15);
      const int sw = (row & 7) << 4;
      bh[fn] = *(const short8*)(BsP + row * 128 + (s16 ^ sw));
      bl[fn] = *(const short8*)(BsP + row * 128 + ((s16 + 16) ^ sw));
    }
    #pragma unroll
    for (int fm = 0; fm < 4; fm++) {
      const int row = wr * 64 + fm * 16 + (lane & 15);
      const int sw = (row & 7) << 4;
      const short8 ah = *(const short8*)(AsP + row * 128 + (s16 ^ sw));
      short8 al;
      if (LH) al = *(const short8*)(AsP + row * 128 + ((s16 + 16) ^ sw));
      #pragma unroll
      for (int fn = 0; fn < 4; fn++) {
        acc[fm][fn] = __builtin_amdgcn_mfma_f32_16x16x32_bf16(ah, bh[fn], acc[fm][fn], 0, 0, 0);
        acc[fm][fn] = __builtin_amdgcn_mfma_f32_16x16x32_bf16(ah, bl[fn], acc[fm][fn], 0, 0, 0);
        if (LH)
          acc[fm][fn] = __builtin_amdgcn_mfma_f32_16x16x32_bf16(al, bh[fn], acc[fm][fn], 0, 0, 0);
      }
    }
    __syncthreads();
  }

  // C/D map: col=lane&15, row=(lane>>4)*4+j
  #pragma unroll
  for (int fm = 0; fm < 4; fm++) {
    #pragma unroll
    for (int fn = 0; fn < 4; fn++) {
      const int col = bn + wc * 64 + fn * 16 + (lane & 15);
      #pragma unroll
      for (int j = 0; j < 4; j++) {
        const int row = bm + wr * 64 + fm * 16 + (lane >> 4) * 4 + j;
        if (row < M) {
          float v = acc[fm][fn][j];
          if (TANH) v = tanhf(v);
          C[(size_t)row * N + col] = v;
        }
      }
    }
  }
}

// ---------------- fused scores + softmax + aggregate ----------------
// One block (512 thr / 8 waves) per row; neigh streamed once through regs.
// Output written directly as panel image (hi/lo bf16, swizzled) for gemm2.
__global__ __launch_bounds__(512) void attn_fused(
    const float* __restrict__ neigh,   // [N, 32, 512]
    const float* __restrict__ x,       // [N, 512] f32
    const void* __restrict__ mask,     // [N, 32] int32 or u8 (see flag)
    const int* __restrict__ mask_is_u8,
    unsigned char* __restrict__ aggP)  // panel image, 2048 B/row
{
  __shared__ float x_s[ND];
  __shared__ float part[8][ND];
  __shared__ float sc_s[NK];
  __shared__ float attn_s[NK];
  __shared__ unsigned char img[2048];
  const int n = blockIdx.x;
  const int tid = threadIdx.x;
  const int wv = tid >> 6;
  const int lane = tid & 63;

  x_s[tid] = x[(size_t)n * ND + tid];
  __syncthreads();

  const float4 xa = *(const float4*)&x_s[lane * 4];
  const float4 xb = *(const float4*)&x_s[256 + lane * 4];

  const float4* nbase = (const float4*)(neigh + ((size_t)n * NK + wv * 4) * ND);
  float4 na[4], nb[4];
  #pragma unroll
  for (int j = 0; j < 4; j++) {
    na[j] = nbase[j * 128 + lane];
    nb[j] = nbase[j * 128 + 64 + lane];
  }

  #pragma unroll
  for (int j = 0; j < 4; j++) {
    float p = na[j].x * xa.x + na[j].y * xa.y + na[j].z * xa.z + na[j].w * xa.w
            + nb[j].x * xb.x + nb[j].y * xb.y + nb[j].z * xb.z + nb[j].w * xb.w;
    #pragma unroll
    for (int off = 32; off; off >>= 1) p += __shfl_xor(p, off);
    if (lane == 0) sc_s[wv * 4 + j] = p;
  }
  __syncthreads();

  if (tid < NK) {
    const int mk = (*mask_is_u8)
        ? (int)((const unsigned char*)mask)[(size_t)n * NK + tid]
        : ((const int*)mask)[(size_t)n * NK + tid];
    float s = mk ? -3.4e38f : sc_s[tid];
    float m = s;
    #pragma unroll
    for (int off = 16; off; off >>= 1) m = fmaxf(m, __shfl_xor(m, off, 32));
    const float p = mk ? 0.f : expf(s - m);
    float t = p;
    #pragma unroll
    for (int off = 16; off; off >>= 1) t += __shfl_xor(t, off, 32);
    attn_s[tid] = p / t;
  }
  __syncthreads();

  float4 acc0 = make_float4(0.f, 0.f, 0.f, 0.f);
  float4 acc1 = make_float4(0.f, 0.f, 0.f, 0.f);
  #pragma unroll
  for (int j = 0; j < 4; j++) {
    const float w = attn_s[wv * 4 + j];
    acc0.x = fmaf(w, na[j].x, acc0.x);
    acc0.y = fmaf(w, na[j].y, acc0.y);
    acc0.z = fmaf(w, na[j].z, acc0.z);
    acc0.w = fmaf(w, na[j].w, acc0.w);
    acc1.x = fmaf(w, nb[j].x, acc1.x);
    acc1.y = fmaf(w, nb[j].y, acc1.y);
    acc1.z = fmaf(w, nb[j].z, acc1.z);
    acc1.w = fmaf(w, nb[j].w, acc1.w);
  }
  *(float4*)&part[wv][lane * 4] = acc0;
  *(float4*)&part[wv][256 + lane * 4] = acc1;
  __syncthreads();
  float ssum = 0.f;
  #pragma unroll
  for (int w = 0; w < 8; w++) ssum += part[w][tid];

  // encode into panel-image row (k = tid)
  {
    const int sw = (n & 7) << 4;
    const int kb = tid >> 5;
    const int bu = ((tid >> 3) & 3) * 32 + (tid & 7) * 2;   // bit4 == 0
    const unsigned short h = f2bf(ssum);
    const unsigned short l = f2bf(ssum - bf2f(h));
    *(unsigned short*)(img + kb * 128 + (bu ^ sw)) = h;
    *(unsigned short*)(img + kb * 128 + ((bu | 16) ^ sw)) = l;
  }
  __syncthreads();
  if (tid < 128) {
    *(uint4*)(aggP + (size_t)n * 2048 + tid * 16) = *(const uint4*)(img + tid * 16);
  }
}

extern "C" void kernel_launch(void* const* d_in, const int* in_sizes, int n_in,
                              void* d_out, int out_size, void* d_ws, size_t ws_size,
                              hipStream_t stream) {
  const float* prev  = (const float*)d_in[0];   // [N, 512]
  const float* neigh = (const float*)d_in[1];   // [N, 32, 512]
  const void*  mask  = d_in[2];                 // [N, 32]
  const float* W1    = (const float*)d_in[3];   // [512, 512]
  const float* Wa    = (const float*)d_in[4];   // [512, 1024]
  float* out = (float*)d_out;
  const int N = in_sizes[0] / ND;               // 20000
  const int Mp = ((N + 127) / 128) * 128;       // 20096

  unsigned char* ws = (unsigned char*)d_ws;
  float*         x     = (float*)ws;                         // N*2048 B
  unsigned char* prevP = ws + (size_t)N * 2048;              // Mp*2048
  unsigned char* aggP  = prevP + (size_t)Mp * 2048;          // Mp*2048
  unsigned char* W1P   = aggP + (size_t)Mp * 2048;           // 512*2048
  unsigned char* WaP   = W1P + (size_t)512 * 2048;           // 512*4096
  int*           flag  = (int*)(WaP + (size_t)512 * 4096);

  hipMemsetAsync(flag, 0, sizeof(int), stream);
  detect_mask_kernel<<<64, 256, 0, stream>>>((const unsigned int*)mask,
                                             (N * NK) / 4, flag);

  // pre-encode all GEMM operands into panel images (single launch)
  convert_panels3<<<2048, 256, 0, stream>>>(prev, prevP, N, Mp, W1, W1P, Wa, WaP);
  if (Mp > N)
    hipMemsetAsync(aggP + (size_t)N * 2048, 0, (size_t)(Mp - N) * 2048, stream);

  const int nwg = (Mp / 128) * 4;  // 1-D grid, bn innermost, XCD-swizzled

  // x = prev @ W1^T  (split-3: score path needs full precision)
  gemm_mfma<false, false, true><<<nwg, 256, 0, stream>>>(prevP, nullptr, W1P, x, N, ND, 16);

  // scores -> softmax -> agg (neigh streamed once; agg emitted as panel image)
  attn_fused<<<N, 512, 0, stream>>>(neigh, x, mask, flag, aggP);

  // out = tanh(concat(agg, prev) @ Wa^T)  (split-2: tanh-output path)
  gemm_mfma<true, true, false><<<nwg, 256, 0, stream>>>(aggP, prevP, WaP, out, N, ND, 32);
}